// Round 3
// baseline (256.919 us; speedup 1.0000x reference)
//
#include <hip/hip_runtime.h>
#include <stdint.h>

#define NCLS 172
#define IGN 255
#define HW 65536          // 256*256
#define NPIX 262144       // 4*256*256
#define EPSV 1e-7f
#define TP 32             // pixels per LDS tile
#define TROWS 192         // 24 staging blocks x 8 rows; rows >=172 are write-only pad
#define TSZ (TROWS * TP)  // floats per tile buffer
#define NTILE 4           // tiles per block -> 128 px/block
#define PIXPERBLK (TP * NTILE)
#define NSTAGE 32         // staged global partial buffers
#define SS 520            // [0,172) inter | [172,344) cnt | [344,516) union | 516 ce | 517 nvalid

__device__ __forceinline__ void gl_lds16(const float* g, float* l) {
    __builtin_amdgcn_global_load_lds(
        (const __attribute__((address_space(1))) void*)g,
        (__attribute__((address_space(3))) void*)l, 16, 0, 0);
}

// Double-buffered fused single-read kernel.
// Loop top: issue next tile's 6 global_load_lds into the other buffer, then
// s_waitcnt vmcnt(6) (wait ONLY the current tile's 6 oldest loads) -> raw
// s_barrier. No vmcnt(0) drain in the main loop: 6 loads stay in flight
// across every compute phase. All intra-loop barriers are lgkmcnt(0)+s_barrier.
__global__ __launch_bounds__(256) void seg_fused(
    const float* __restrict__ pred, const int* __restrict__ tgt,
    float* __restrict__ part)
{
    __shared__ float tile[2 * TSZ];        // 49152 B, linear (DMA dest)
    __shared__ float sPart[128];
    __shared__ float sInvs[TP];
    __shared__ int   sTgt[PIXPERBLK];
    __shared__ float sInter[NCLS];
    __shared__ unsigned int sCnt[NCLS];

    const int tid   = threadIdx.x;
    const int lane  = tid & 63;
    const int wv    = tid >> 6;
    const int p     = tid & 31;            // pixel within tile
    const int chunk = tid >> 5;            // class chunk 0..7 (c = chunk + 8k)

    for (int i = tid; i < NCLS; i += 256) { sInter[i] = 0.f; sCnt[i] = 0u; }
    const int pix0 = blockIdx.x * PIXPERBLK;
    if (tid < PIXPERBLK) sTgt[tid] = tgt[pix0 + tid];   // no global loads inside loop

    const int b   = pix0 >> 16;
    const int hw0 = pix0 & (HW - 1);
    const float* gb = pred + (size_t)b * NCLS * HW + hw0;

    // staging lane decomposition: 64 lanes x 16B = 8 class rows (128B each)
    const int scb = lane >> 3;             // class sub-row 0..7
    const int spo = (lane & 7) << 2;       // pixel float offset 0..28

    // ---- prologue: stage tile 0 into buffer 0 (exactly 6 instrs per wave) ----
    #pragma unroll
    for (int k = 0; k < 6; ++k) {
        const int ib = wv + 4 * k;         // 0..23 across the 4 waves
        int cb = ib * 8 + scb; if (cb > NCLS - 1) cb = NCLS - 1;
        gl_lds16(gb + (size_t)cb * HW + spo, &tile[ib * (8 * TP)]);
    }

    float unionAcc = 0.f, ceAcc = 0.f, nvAcc = 0.f;

    for (int tI = 0; tI < NTILE; ++tI) {
        const int tb = (tI & 1) * TSZ;

        // ---- prefetch next tile into the other buffer, then wait current ----
        if (tI + 1 < NTILE) {
            const float* gt = gb + (tI + 1) * TP;
            const int nb = ((tI + 1) & 1) * TSZ;
            #pragma unroll
            for (int k = 0; k < 6; ++k) {
                const int ib = wv + 4 * k;
                int cb = ib * 8 + scb; if (cb > NCLS - 1) cb = NCLS - 1;
                gl_lds16(gt + (size_t)cb * HW + spo, &tile[nb + ib * (8 * TP)]);
            }
            asm volatile("s_waitcnt vmcnt(6) lgkmcnt(0)" ::: "memory");
        } else {
            asm volatile("s_waitcnt vmcnt(0) lgkmcnt(0)" ::: "memory");
        }
        __builtin_amdgcn_s_barrier();
        __builtin_amdgcn_sched_barrier(0);

        // ---- phase 1: sumexp over this chunk's classes, exp written back ----
        float s0 = 0.f, s1 = 0.f;
        #pragma unroll
        for (int k = 0; k < 20; k += 2) {
            const int i0 = tb + (chunk + 8 * k) * TP + p;
            const int i1 = tb + (chunk + 8 * k + 8) * TP + p;
            const float e0 = __expf(tile[i0]);
            const float e1 = __expf(tile[i1]);
            tile[i0] = e0; tile[i1] = e1;
            s0 += e0; s1 += e1;
        }
        {   const int i0 = tb + (chunk + 160) * TP + p;
            const float e = __expf(tile[i0]); tile[i0] = e; s0 += e; }
        if (chunk < 4) {                   // classes 168..171
            const int i1 = tb + (chunk + 168) * TP + p;
            const float e = __expf(tile[i1]); tile[i1] = e; s1 += e;
        }
        float sv = s0 + s1;
        sv += __shfl_down(sv, 32, 64);     // combine the wave's two chunks
        if (lane < 32) sPart[wv * 32 + p] = sv;
        asm volatile("s_waitcnt lgkmcnt(0)" ::: "memory");
        __builtin_amdgcn_s_barrier();
        __builtin_amdgcn_sched_barrier(0);

        // ---- finalize: invs, CE, inter/cnt (32 threads) ----
        if (tid < 32) {
            const float s    = (sPart[p] + sPart[32 + p]) + (sPart[64 + p] + sPart[96 + p]);
            const float invs = 1.0f / s;
            sInvs[p] = invs;
            const int  t     = sTgt[tI * TP + p];
            const bool valid = (t != IGN);
            const int  st    = valid ? t : 0;
            const float et   = tile[tb + st * TP + p];  // exp(x_t), banks p
            const float pt   = et * invs;
            float nll = valid ? -__logf(pt) : 0.f;
            float nv  = valid ? 1.f : 0.f;
            if (valid) { atomicAdd(&sInter[st], pt); atomicAdd(&sCnt[st], 1u); }
            #pragma unroll
            for (int off = 16; off > 0; off >>= 1) {
                nll += __shfl_down(nll, off, 64);
                nv  += __shfl_down(nv,  off, 64);
            }
            if (tid == 0) { ceAcc += nll; nvAcc += nv; }
        }
        asm volatile("s_waitcnt lgkmcnt(0)" ::: "memory");
        __builtin_amdgcn_s_barrier();
        __builtin_amdgcn_sched_barrier(0);

        // ---- phase 2: per-class union, pure fma on cached exp, diagonal walk ----
        if (tid < NCLS) {
            const int tr = tb + tid * TP;
            float u0 = 0.f, u1 = 0.f;
            #pragma unroll
            for (int k = 0; k < TP; k += 2) {
                const int p0 = (tid + k)     & (TP - 1);
                const int p1 = (tid + k + 1) & (TP - 1);
                u0 += tile[tr + p0] * sInvs[p0];
                u1 += tile[tr + p1] * sInvs[p1];
            }
            unionAcc += u0 + u1;
        }
        // reuse guard: next iteration's DMA overwrites the buffer just read
        asm volatile("s_waitcnt lgkmcnt(0)" ::: "memory");
        __builtin_amdgcn_s_barrier();
        __builtin_amdgcn_sched_barrier(0);
    }

    // ---- flush per-block partials to staged global buffers ----
    float* pb = part + (size_t)(blockIdx.x & (NSTAGE - 1)) * SS;
    for (int i = tid; i < NCLS; i += 256) {
        const float vi = sInter[i];
        if (vi != 0.f) atomicAdd(&pb[i], vi);
        const unsigned int ci = sCnt[i];
        if (ci != 0u) atomicAdd(&pb[NCLS + i], (float)ci);
    }
    if (tid < NCLS) atomicAdd(&pb[344 + tid], unionAcc);
    if (tid == 0) { atomicAdd(&pb[516], ceAcc); atomicAdd(&pb[517], nvAcc); }
}

__global__ __launch_bounds__(256) void seg_fin(
    const float* __restrict__ part, float* __restrict__ out)
{
    __shared__ float sT[256], sN[256];
    const int tid = threadIdx.x;
    float term = 0.f, nv = 0.f;
    if (tid < NCLS) {
        float inter = 0.f, cnt = 0.f, uni = 0.f;
        for (int st = 0; st < NSTAGE; ++st) {
            inter += part[st * SS + tid];
            cnt   += part[st * SS + NCLS + tid];
            uni   += part[st * SS + 344 + tid];
        }
        const float u = uni + cnt;
        if (u > 0.f) { term = (2.f * inter + EPSV) / (u + EPSV); nv = 1.f; }
    }
    sT[tid] = term; sN[tid] = nv;
    __syncthreads();
    #pragma unroll
    for (int s2 = 128; s2 > 0; s2 >>= 1) {
        if (tid < s2) { sT[tid] += sT[tid + s2]; sN[tid] += sN[tid + s2]; }
        __syncthreads();
    }
    if (tid == 0) {
        float ce = 0.f, nvl = 0.f;
        for (int st = 0; st < NSTAGE; ++st) {
            ce  += part[st * SS + 516];
            nvl += part[st * SS + 517];
        }
        const float ceo  = ce / fmaxf(nvl, 1.f);
        const float dice = (sN[0] > 0.f) ? (1.f - sT[0] / fmaxf(sN[0], 1.f)) : 0.f;
        out[0] = ceo + 0.5f * dice;
    }
}

extern "C" void kernel_launch(void* const* d_in, const int* in_sizes, int n_in,
                              void* d_out, int out_size, void* d_ws, size_t ws_size,
                              hipStream_t stream) {
    const float* pred = (const float*)d_in[0];
    const int*   tgt  = (const int*)d_in[1];
    float* out  = (float*)d_out;
    float* part = (float*)d_ws;

    hipMemsetAsync(d_ws, 0, NSTAGE * SS * sizeof(float), stream);
    seg_fused<<<NPIX / PIXPERBLK, 256, 0, stream>>>(pred, tgt, part);
    seg_fin<<<1, 256, 0, stream>>>(part, out);
}